// Round 11
// baseline (2125.616 us; speedup 1.0000x reference)
//
#include <hip/hip_runtime.h>
#include <hip/hip_bf16.h>
#include <stdint.h>

#define N_NODES 50000
#define N_EDGES 800000
#define N_TILES (N_EDGES / 16)

typedef unsigned int uint32;
typedef __fp16   fp16x2 __attribute__((ext_vector_type(2)));
typedef _Float16 half8v __attribute__((ext_vector_type(8)));
typedef float    f32x4  __attribute__((ext_vector_type(4)));
typedef uint32   u32x2  __attribute__((ext_vector_type(2)));
typedef uint32   u32x4  __attribute__((ext_vector_type(4)));

union H2U { uint32 u; fp16x2 h; };
union H8U { u32x4 u; half8v h; };

__device__ __forceinline__ uint32 pk16(float lo, float hi) {
    H2U z; z.h = __builtin_amdgcn_cvt_pkrtz(lo, hi); return z.u;
}
__device__ __forceinline__ float h16lo(uint32 u) { H2U z; z.u = u; return (float)z.h[0]; }
__device__ __forceinline__ float h16hi(uint32 u) { H2U z; z.u = u; return (float)z.h[1]; }
__device__ __forceinline__ float silu(float v) { return v / (1.0f + __expf(-v)); }

// ---------- Kernel 0: zero scratch ------------------------------------------
__global__ __launch_bounds__(256) void zero_ws(uint32* __restrict__ p, int n) {
    int i = blockIdx.x * 256 + threadIdx.x;
    int stride = gridDim.x * 256;
    for (; i < n; i += stride) p[i] = 0u;
}

// ---------- Sort kernels: counting sort of edges by dst ---------------------
__global__ __launch_bounds__(256) void hist_dst(const int* __restrict__ ei,
                                                uint32* __restrict__ hist) {
    int i = blockIdx.x * 256 + threadIdx.x, s = gridDim.x * 256;
    for (; i < N_EDGES; i += s) atomicAdd(&hist[ei[N_EDGES + i]], 1u);
}

__global__ __launch_bounds__(1024) void scan_hist(const uint32* __restrict__ hist,
                                                  uint32* __restrict__ cursor) {
    __shared__ uint32 part[1024];
    const int t = threadIdx.x;
    const int CH = (N_NODES + 1023) / 1024;
    const int lo = t * CH;
    const int hi = min(lo + CH, N_NODES);
    uint32 s = 0;
    for (int i = lo; i < hi; ++i) s += hist[i];
    part[t] = s;
    __syncthreads();
    for (int off = 1; off < 1024; off <<= 1) {
        uint32 v = (t >= off) ? part[t - off] : 0u;
        __syncthreads();
        part[t] += v;
        __syncthreads();
    }
    uint32 run = (t == 0) ? 0u : part[t - 1];
    for (int i = lo; i < hi; ++i) { const uint32 c = hist[i]; cursor[i] = run; run += c; }
}

__global__ __launch_bounds__(256) void scatter_perm(const int* __restrict__ ei,
                                                    uint32* __restrict__ cursor,
                                                    uint32* __restrict__ perm) {
    int i = blockIdx.x * 256 + threadIdx.x, s = gridDim.x * 256;
    for (; i < N_EDGES; i += s) {
        const int d = ei[N_EDGES + i];
        const uint32 pos = atomicAdd(&cursor[d], 1u);
        perm[pos] = (uint32)i;
    }
}

// ---------- Kernel 0b: weight fragments (f16x2) in ws -----------------------
__global__ __launch_bounds__(256) void prep_frags(
    const float* __restrict__ W2, const float* __restrict__ Wc1,
    const float* __restrict__ W1, const float* __restrict__ b1,
    uint32* __restrict__ W2A, uint32* __restrict__ WC1A, uint32* __restrict__ W1TF)
{
    int i = blockIdx.x * 256 + threadIdx.x;
    if (i < 8192) {
        const int p = i & 3, l = (i >> 2) & 63, f = i >> 8;
        const int ot = f >> 2, kb = f & 3;
        const int k0 = kb * 32 + (l >> 4) * 8 + 2 * p;
        const int o  = (l & 15) + ot * 16;
        W2A[i]  = pk16(W2[(size_t)k0 * 128 + o],  W2[(size_t)(k0 + 1) * 128 + o]);
        WC1A[i] = pk16(Wc1[(size_t)k0 * 128 + o], Wc1[(size_t)(k0 + 1) * 128 + o]);
    }
    if (i < 5 * 64) {
        const int row = i >> 6, p = i & 63;
        if (row < 4)
            W1TF[i] = pk16(W1[(size_t)(256 + row) * 128 + 2 * p],
                           W1[(size_t)(256 + row) * 128 + 2 * p + 1]);
        else
            W1TF[i] = pk16(b1[2 * p], b1[2 * p + 1]);
    }
}

// ---------- Kernel 1: A = h@W1[0:128], B = h@W1[128:256]  (4 nodes/wave) ----
__global__ __launch_bounds__(256) void pre_proj(
    const float* __restrict__ h, const float* __restrict__ W1,
    uint32* __restrict__ A, uint32* __restrict__ B)
{
    const int lane = threadIdx.x & 63;
    const int wave = blockIdx.x * 4 + (threadIdx.x >> 6);
    const int n0 = wave * 4;
    if (n0 >= N_NODES) return;
    const int j0 = lane * 2;

    float ha[4], hb[4];
#pragma unroll
    for (int i = 0; i < 4; ++i) {
        ha[i] = h[(size_t)(n0 + i) * 128 + lane];
        hb[i] = h[(size_t)(n0 + i) * 128 + 64 + lane];
    }
    float2 accA[4], accB[4];
#pragma unroll
    for (int i = 0; i < 4; ++i) { accA[i] = make_float2(0.f, 0.f); accB[i] = make_float2(0.f, 0.f); }

#pragma unroll 8
    for (int k = 0; k < 64; ++k) {
        const float2 wa0 = *(const float2*)(W1 + (size_t)k * 128 + j0);
        const float2 wa1 = *(const float2*)(W1 + (size_t)(64 + k) * 128 + j0);
        const float2 wb0 = *(const float2*)(W1 + (size_t)(128 + k) * 128 + j0);
        const float2 wb1 = *(const float2*)(W1 + (size_t)(192 + k) * 128 + j0);
#pragma unroll
        for (int i = 0; i < 4; ++i) {
            const float va = __shfl(ha[i], k);
            const float vb = __shfl(hb[i], k);
            accA[i].x += va * wa0.x + vb * wa1.x;
            accA[i].y += va * wa0.y + vb * wa1.y;
            accB[i].x += va * wb0.x + vb * wb1.x;
            accB[i].y += va * wb0.y + vb * wb1.y;
        }
    }
#pragma unroll
    for (int i = 0; i < 4; ++i) {
        A[(size_t)(n0 + i) * 64 + lane] = pk16(accA[i].x, accA[i].y);
        B[(size_t)(n0 + i) * 64 + lane] = pk16(accB[i].x, accB[i].y);
    }
}

// ---------- Kernel 2: MFMA edge kernel, dst-sorted + XCD-localized ----------
// Each wave owns a CONTIGUOUS range of dst-sorted tiles; blocks are swizzled
// so each XCD handles one contiguous eighth -> its agg_msg slice (3.2 MB)
// stays resident in that XCD's 4 MB L2 (atomics become local RMW).
#define EWAVES 4
#define NBLK   1024
#define NWAVES (NBLK * EWAVES)
#define CHUNK  ((N_TILES + NWAVES - 1) / NWAVES)
__global__ __launch_bounds__(256, 3) void edge_mfma(
    const int* __restrict__ ei, const float* __restrict__ x,
    const float* __restrict__ eattr, const uint32* __restrict__ perm,
    const float* __restrict__ b2, const float* __restrict__ bc1,
    const float* __restrict__ Wc2, const float* __restrict__ bc2,
    const uint32* __restrict__ W2A, const uint32* __restrict__ WC1A,
    const uint32* __restrict__ W1TF,
    const uint32* __restrict__ Apk, const uint32* __restrict__ Bpk,
    float* __restrict__ agg_msg, float* __restrict__ agg_coord)
{
    __shared__ uint32 sM2[EWAVES * 16 * 68];

    const int tid   = threadIdx.x;
    const int lane  = tid & 63;
    const int wv    = tid >> 6;
    const int quad  = lane >> 4;
    const int e_own = lane & 15;
    const int swb   = wv * (16 * 68);
    const float bc2f = bc2[0];

    // XCD swizzle: blocks 0..1023 -> xcd = blk&7 owns contiguous slice
    const int sblk = (blockIdx.x & 7) * (NBLK / 8) + (blockIdx.x >> 3);
    const int wave = sblk * EWAVES + wv;
    const int t0 = wave * CHUNK;
    const int t1 = min(t0 + CHUNK, N_TILES);
    if (t0 >= N_TILES) return;

    int nsrc, ndst; float nrx, nry, nrz, ndsq, ne0, ne1, ne2;
    u32x4 av[4], bv[4];
    half8v m1h[4];

    auto load_tile = [&](int tt) {
        const int eidx = (int)perm[tt * 16 + e_own];
        nsrc = ei[eidx];
        ndst = ei[N_EDGES + eidx];
        nrx = x[nsrc * 3 + 0] - x[ndst * 3 + 0];
        nry = x[nsrc * 3 + 1] - x[ndst * 3 + 1];
        nrz = x[nsrc * 3 + 2] - x[ndst * 3 + 2];
        ndsq = nrx * nrx + nry * nry + nrz * nrz;
        ne0 = eattr[(size_t)eidx * 3 + 0];
        ne1 = eattr[(size_t)eidx * 3 + 1];
        ne2 = eattr[(size_t)eidx * 3 + 2];
#pragma unroll
        for (int kb = 0; kb < 4; ++kb) {
            av[kb] = *(const u32x4*)&Apk[(size_t)nsrc * 64 + kb * 16 + quad * 4];
            bv[kb] = *(const u32x4*)&Bpk[(size_t)ndst * 64 + kb * 16 + quad * 4];
        }
    };

    auto compute_m1 = [&]() {
        const _Float16 s0 = (_Float16)ne0, s1 = (_Float16)ne1;
        const _Float16 s2 = (_Float16)ne2, sd = (_Float16)ndsq;
#pragma unroll
        for (int kb = 0; kb < 4; ++kb) {
            const int base = kb * 16 + quad * 4;
            H8U a, b, w0, w1, w2, w3, w4;
            a.u  = av[kb]; b.u = bv[kb];
            w0.u = *(const u32x4*)&W1TF[0 * 64 + base];
            w1.u = *(const u32x4*)&W1TF[1 * 64 + base];
            w2.u = *(const u32x4*)&W1TF[2 * 64 + base];
            w3.u = *(const u32x4*)&W1TF[3 * 64 + base];
            w4.u = *(const u32x4*)&W1TF[4 * 64 + base];
            half8v s = a.h + b.h + w4.h;
            s += w0.h * s0;
            s += w1.h * s1;
            s += w2.h * s2;
            s += w3.h * sd;
            half8v m;
#pragma unroll
            for (int j = 0; j < 8; ++j) m[j] = (_Float16)silu((float)s[j]);
            m1h[kb] = m;
        }
    };

    load_tile(t0);
    compute_m1();

    for (int t = t0; t < t1; ++t) {
        const int   dst_own = ndst;
        const float rxo = nrx, ryo = nry, rzo = nrz;
        const bool  more = (t + 1 < t1);
        if (more) load_tile(t + 1);         // gathers issue BEFORE atomics below

        // ---- matmul 1 ------------------------------------------------------
        f32x4 acc[8];
#pragma unroll
        for (int ot = 0; ot < 8; ++ot) acc[ot] = 0.0f;
#pragma unroll 2
        for (int ot = 0; ot < 8; ++ot) {
#pragma unroll
            for (int kb = 0; kb < 4; ++kb) {
                H8U w; w.u = *(const u32x4*)(W2A + (size_t)((ot * 4 + kb) * 64 + lane) * 4);
                acc[ot] = __builtin_amdgcn_mfma_f32_16x16x32_f16(w.h, m1h[kb], acc[ot], 0, 0, 0);
            }
        }

        // ---- epilogue 1: m2 -> LDS transpose stage -------------------------
#pragma unroll
        for (int ot = 0; ot < 8; ++ot) {
            const f32x4 bb = *(const f32x4*)(b2 + 16 * ot + 4 * quad);
            const float m0  = silu(acc[ot][0] + bb[0]);
            const float m1_ = silu(acc[ot][1] + bb[1]);
            const float m2_ = silu(acc[ot][2] + bb[2]);
            const float m3_ = silu(acc[ot][3] + bb[3]);
            u32x2 pair;
            pair[0] = pk16(m0, m1_);
            pair[1] = pk16(m2_, m3_);
            *(u32x2*)&sM2[swb + e_own * 68 + 8 * ot + 2 * quad] = pair;
        }

        // ---- B-frags of m2^T ----------------------------------------------
        H8U m2f[4];
#pragma unroll
        for (int kb = 0; kb < 4; ++kb)
            m2f[kb].u = *(const u32x4*)&sM2[swb + e_own * 68 + kb * 16 + quad * 4];

        // ---- matmul 2 ------------------------------------------------------
#pragma unroll
        for (int ot = 0; ot < 8; ++ot) acc[ot] = 0.0f;
#pragma unroll 2
        for (int ot = 0; ot < 8; ++ot) {
#pragma unroll
            for (int kb = 0; kb < 4; ++kb) {
                H8U w; w.u = *(const u32x4*)(WC1A + (size_t)((ot * 4 + kb) * 64 + lane) * 4);
                acc[ot] = __builtin_amdgcn_mfma_f32_16x16x32_f16(w.h, m2f[kb].h, acc[ot], 0, 0, 0);
            }
        }

        // ---- coalesced agg_msg atomics (dst-sorted -> L2-local) ------------
#pragma unroll
        for (int e = 0; e < 16; ++e) {
            const int de = __shfl(dst_own, e);
            const uint32 v = sM2[swb + e * 68 + lane];
            atomicAdd(&agg_msg[(size_t)de * 128 + 2 * lane],     h16lo(v));
            atomicAdd(&agg_msg[(size_t)de * 128 + 2 * lane + 1], h16hi(v));
        }

        // ---- epilogue 2: coord weight + atomics ----------------------------
        float partial = 0.0f;
#pragma unroll
        for (int ot = 0; ot < 8; ++ot) {
            const f32x4 bb = *(const f32x4*)(bc1 + 16 * ot + 4 * quad);
            const f32x4 wc = *(const f32x4*)(Wc2 + 16 * ot + 4 * quad);
#pragma unroll
            for (int r = 0; r < 4; ++r)
                partial += silu(acc[ot][r] + bb[r]) * wc[r];
        }
        partial += __shfl_xor(partial, 16);
        partial += __shfl_xor(partial, 32);
        const float cw = partial + bc2f;

        if (quad < 3) {
            const float rsel = (quad == 0) ? rxo : ((quad == 1) ? ryo : rzo);
            atomicAdd(&agg_coord[dst_own * 3 + quad], rsel * cw);
        }

        if (more) compute_m1();
    }
}

// ---------- Kernel 3: node MLP + layernorm + x_out  (4 nodes/wave) ----------
__global__ __launch_bounds__(256) void node_kernel(
    const float* __restrict__ h, const float* __restrict__ x,
    const float* __restrict__ Wn1, const float* __restrict__ bn1,
    const float* __restrict__ Wn2, const float* __restrict__ bn2,
    const float* __restrict__ gamma, const float* __restrict__ beta,
    const float* __restrict__ agg_msg, const float* __restrict__ agg_coord,
    const uint32* __restrict__ hist, float* __restrict__ out)
{
    const int lane = threadIdx.x & 63;
    const int wave = blockIdx.x * 4 + (threadIdx.x >> 6);
    const int n0 = wave * 4;
    if (n0 >= N_NODES) return;
    const int j0 = lane * 2;

    float r0[4], r1[4], r2[4], r3[4];
#pragma unroll
    for (int i = 0; i < 4; ++i) {
        r0[i] = h[(size_t)(n0 + i) * 128 + lane];
        r1[i] = h[(size_t)(n0 + i) * 128 + 64 + lane];
        r2[i] = agg_msg[(size_t)(n0 + i) * 128 + lane];
        r3[i] = agg_msg[(size_t)(n0 + i) * 128 + 64 + lane];
    }

    const float2 bn1v = *(const float2*)(bn1 + j0);
    float2 a[4];
#pragma unroll
    for (int i = 0; i < 4; ++i) { a[i].x = bn1v.x; a[i].y = bn1v.y; }

#pragma unroll 8
    for (int k = 0; k < 64; ++k) {
        const float2 w0 = *(const float2*)(Wn1 + (size_t)k * 128 + j0);
        const float2 w1 = *(const float2*)(Wn1 + (size_t)(64 + k) * 128 + j0);
        const float2 w2 = *(const float2*)(Wn1 + (size_t)(128 + k) * 128 + j0);
        const float2 w3 = *(const float2*)(Wn1 + (size_t)(192 + k) * 128 + j0);
#pragma unroll
        for (int i = 0; i < 4; ++i) {
            const float v0 = __shfl(r0[i], k);
            const float v1 = __shfl(r1[i], k);
            const float v2 = __shfl(r2[i], k);
            const float v3 = __shfl(r3[i], k);
            a[i].x += v0 * w0.x + v1 * w1.x + v2 * w2.x + v3 * w3.x;
            a[i].y += v0 * w0.y + v1 * w1.y + v2 * w2.y + v3 * w3.y;
        }
    }

    float2 z[4];
#pragma unroll
    for (int i = 0; i < 4; ++i) { z[i].x = silu(a[i].x); z[i].y = silu(a[i].y); }

    const float2 bn2v = *(const float2*)(bn2 + j0);
    float2 u[4];
#pragma unroll
    for (int i = 0; i < 4; ++i) { u[i].x = bn2v.x; u[i].y = bn2v.y; }

#pragma unroll 8
    for (int q = 0; q < 64; ++q) {
        const float2 w0 = *(const float2*)(Wn2 + (size_t)(2 * q) * 128 + j0);
        const float2 w1 = *(const float2*)(Wn2 + (size_t)(2 * q + 1) * 128 + j0);
#pragma unroll
        for (int i = 0; i < 4; ++i) {
            const float va = __shfl(z[i].x, q);
            const float vb = __shfl(z[i].y, q);
            u[i].x += va * w0.x + vb * w1.x;
            u[i].y += va * w0.y + vb * w1.y;
        }
    }

    const float2 gv = *(const float2*)(gamma + j0);
    const float2 bv = *(const float2*)(beta + j0);
#pragma unroll
    for (int i = 0; i < 4; ++i) {
        const float2 hv = *(const float2*)(h + (size_t)(n0 + i) * 128 + j0);
        const float y0 = hv.x + u[i].x;
        const float y1 = hv.y + u[i].y;
        float s1 = y0 + y1, s2 = y0 * y0 + y1 * y1;
#pragma unroll
        for (int off = 32; off; off >>= 1) { s1 += __shfl_xor(s1, off); s2 += __shfl_xor(s2, off); }
        const float mu  = s1 * (1.0f / 128.0f);
        const float var = s2 * (1.0f / 128.0f) - mu * mu;
        const float rs  = rsqrtf(var + 1e-5f);
        float2 o;
        o.x = (y0 - mu) * rs * gv.x + bv.x;
        o.y = (y1 - mu) * rs * gv.y + bv.y;
        *(float2*)(out + (size_t)(n0 + i) * 128 + j0) = o;
    }

    const int g = lane >> 4, r = lane & 15;
    if (r < 3) {
        const int n = n0 + g;
        const float c = (float)max(hist[n], 1u);
        out[(size_t)N_NODES * 128 + (size_t)n * 3 + r] =
            x[n * 3 + r] + agg_coord[n * 3 + r] / c;
    }
}

extern "C" void kernel_launch(void* const* d_in, const int* in_sizes, int n_in,
                              void* d_out, int out_size, void* d_ws, size_t ws_size,
                              hipStream_t stream)
{
    const float* h     = (const float*)d_in[0];
    const float* x     = (const float*)d_in[1];
    const int*   ei    = (const int*)d_in[2];
    const float* eattr = (const float*)d_in[3];
    const float* W1    = (const float*)d_in[4];
    const float* b1    = (const float*)d_in[5];
    const float* W2    = (const float*)d_in[6];
    const float* b2    = (const float*)d_in[7];
    const float* Wc1   = (const float*)d_in[8];
    const float* bc1   = (const float*)d_in[9];
    const float* Wc2   = (const float*)d_in[10];
    const float* bc2   = (const float*)d_in[11];
    const float* Wn1   = (const float*)d_in[12];
    const float* bn1   = (const float*)d_in[13];
    const float* Wn2   = (const float*)d_in[14];
    const float* bn2   = (const float*)d_in[15];
    const float* gamma = (const float*)d_in[16];
    const float* beta  = (const float*)d_in[17];

    // ws layout (~56 MB):
    uint32* A        = (uint32*)d_ws;                      // N*64 u32 (f16x2)
    uint32* B        = A + (size_t)N_NODES * 64;           // N*64 u32
    float* agg_msg   = (float*)(B + (size_t)N_NODES * 64); // N*128 f32 (zeroed)
    float* agg_coord = agg_msg + (size_t)N_NODES * 128;    // N*3 f32  (zeroed)
    uint32* hist     = (uint32*)(agg_coord + (size_t)N_NODES * 3); // N u32 (zeroed)
    uint32* cursor   = hist + N_NODES;                     // N u32
    uint32* perm     = cursor + N_NODES;                   // E u32
    uint32* W2A      = perm + N_EDGES;                     // 8192 u32
    uint32* WC1A     = W2A + 8192;                         // 8192 u32
    uint32* W1TF     = WC1A + 8192;                        // 320 u32

    const int zero_elems = N_NODES * 128 + N_NODES * 3 + N_NODES; // agg_msg+coord+hist
    zero_ws<<<512, 256, 0, stream>>>((uint32*)agg_msg, zero_elems);
    hist_dst<<<1024, 256, 0, stream>>>(ei, hist);
    scan_hist<<<1, 1024, 0, stream>>>(hist, cursor);
    scatter_perm<<<1024, 256, 0, stream>>>(ei, cursor, perm);
    prep_frags<<<32, 256, 0, stream>>>(W2, Wc1, W1, b1, W2A, WC1A, W1TF);
    pre_proj<<<3125, 256, 0, stream>>>(h, W1, A, B);
    edge_mfma<<<NBLK, 256, 0, stream>>>(ei, x, eattr, perm, b2, bc1, Wc2, bc2,
                                        W2A, WC1A, W1TF, A, B,
                                        agg_msg, agg_coord);
    node_kernel<<<3125, 256, 0, stream>>>(h, x, Wn1, bn1, Wn2, bn2,
                                          gamma, beta, agg_msg, agg_coord,
                                          hist, (float*)d_out);
}